// Round 1
// baseline (194.909 us; speedup 1.0000x reference)
//
#include <hip/hip_runtime.h>
#include <stdint.h>

#pragma clang fp contract(off)

#define C_CLASSES 21
#define TOPK 100
#define NBINS 1024
#define CAND_CAP 1024

__device__ __forceinline__ float arm_pos_f(float c0, float c1) {
#pragma clang fp contract(off)
    // jax.nn.softmax over 2 elems, take [...,1]
    float m = fmaxf(c0, c1);
    float e0 = expf(c0 - m);
    float e1 = expf(c1 - m);
    return e1 / (e0 + e1);
}

__device__ __forceinline__ void decode_box(const float* __restrict__ priors,
                                           const float* __restrict__ bi_loc,
                                           const float* __restrict__ ml_loc,
                                           long long base, int p,
                                           float4* box, float* area) {
#pragma clang fp contract(off)
    float4 pr = *(const float4*)(priors + (size_t)p * 4);
    float4 av = *(const float4*)(bi_loc + (size_t)(base + p) * 4);
    float4 mv = *(const float4*)(ml_loc + (size_t)(base + p) * 4);
    // refined prior (center form), ARM_VAR = (0.1, 0.2)
    float rx = pr.x + av.x * 0.1f * pr.z;
    float ry = pr.y + av.y * 0.1f * pr.w;
    float rw = pr.z * expf(av.z * 0.2f);
    float rh = pr.w * expf(av.w * 0.2f);
    // ODM decode (corner form), ODM_VAR = (0.1, 0.2)
    float ox = rx + mv.x * 0.1f * rw;
    float oy = ry + mv.y * 0.1f * rh;
    float ow = rw * expf(mv.z * 0.2f);
    float oh = rh * expf(mv.w * 0.2f);
    box->x = ox - ow * 0.5f;
    box->y = oy - oh * 0.5f;
    box->z = ox + ow * 0.5f;
    box->w = oy + oh * 0.5f;
    *area = (box->z - box->x) * (box->w - box->y);
}

__device__ __forceinline__ float iou_f(float4 a, float aA,
                                       float sx1, float sy1, float sx2, float sy2,
                                       float sA) {
#pragma clang fp contract(off)
    float tlx = fmaxf(a.x, sx1);
    float tly = fmaxf(a.y, sy1);
    float brx = fminf(a.z, sx2);
    float bry = fminf(a.w, sy2);
    float w = brx - tlx;
    float h = bry - tly;
    w = fmaxf(w, 0.0f);
    h = fmaxf(h, 0.0f);
    float inter = w * h;
    float uni = sA + aA - inter;   // area[sel] + area[me] - inter
    uni = fmaxf(uni, 1e-12f);
    return inter / uni;
}

__global__ __launch_bounds__(256) void detect_kernel(
    const float* __restrict__ bi_loc,
    const float* __restrict__ bi_conf,
    const float* __restrict__ ml_loc,
    const float* __restrict__ ml_conf,
    const float* __restrict__ priors,
    float* __restrict__ out, int B, int P) {
#pragma clang fp contract(off)
    __shared__ uint32_t hist[NBINS];
    __shared__ uint32_t sfx[256];
    __shared__ uint64_t keys[CAND_CAP];
    __shared__ int cutbin_s;
    __shared__ int cnt_s;

    const int bid = blockIdx.x;
    const int b = bid / (C_CLASSES - 1);
    const int c = bid % (C_CLASSES - 1) + 1;
    const int tid = threadIdx.x;

    // zero own output slab; c==1 blocks also zero the background-class slab
    float* slab = out + (size_t)(b * C_CLASSES + c) * TOPK * 5;
    for (int i = tid; i < TOPK * 5; i += 256) slab[i] = 0.0f;
    if (c == 1) {
        float* slab0 = out + (size_t)(b * C_CLASSES) * TOPK * 5;
        for (int i = tid; i < TOPK * 5; i += 256) slab0[i] = 0.0f;
    }

    for (int i = tid; i < NBINS; i += 256) hist[i] = 0;
    if (tid == 0) cnt_s = 0;
    __syncthreads();

    const float* mc = ml_conf + (size_t)b * P * C_CLASSES;
    const float* bc = bi_conf + (size_t)b * P * 2;

    // ---- pass 1: histogram of valid scores (score in (0.3, 1)) ----
    for (int p = tid; p < P; p += 256) {
        float conf = mc[(size_t)p * C_CLASSES + c];
        if (conf > 0.3f) {
            float c0 = bc[2 * p], c1 = bc[2 * p + 1];
            if (arm_pos_f(c0, c1) >= 0.01f) {
                int bin = (int)(conf * 1024.0f);
                bin = bin > (NBINS - 1) ? (NBINS - 1) : bin;
                atomicAdd(&hist[bin], 1u);
            }
        }
    }
    __syncthreads();

    // ---- suffix sums over 4-bin chunks ----
    uint32_t chunk = hist[4 * tid] + hist[4 * tid + 1] + hist[4 * tid + 2] + hist[4 * tid + 3];
    sfx[tid] = chunk;
    __syncthreads();
    for (int off = 1; off < 256; off <<= 1) {
        uint32_t v = (tid + off < 256) ? sfx[tid + off] : 0u;
        __syncthreads();
        sfx[tid] += v;
        __syncthreads();
    }
    const uint32_t total = sfx[0];
    const uint32_t target = total < TOPK ? total : TOPK;
    if (total == 0) return;  // block-uniform; slab already zeroed

    // ---- find cutoff bin: largest bin with count_ge(bin) >= target ----
    {
        uint32_t above = (tid < 255) ? sfx[tid + 1] : 0u;
        uint32_t h0 = hist[4 * tid], h1 = hist[4 * tid + 1];
        uint32_t h2 = hist[4 * tid + 2], h3 = hist[4 * tid + 3];
        uint32_t cge3 = above + h3;
        uint32_t cge2 = cge3 + h2;
        uint32_t cge1 = cge2 + h1;
        uint32_t cge0 = cge1 + h0;
        if (cge3 >= target && above < target) cutbin_s = 4 * tid + 3;
        else if (cge2 >= target && cge3 < target) cutbin_s = 4 * tid + 2;
        else if (cge1 >= target && cge2 < target) cutbin_s = 4 * tid + 1;
        else if (cge0 >= target && cge1 < target) cutbin_s = 4 * tid;
    }
    __syncthreads();
    const int cutbin = cutbin_s;

    // ---- pass 2: collect candidates with bin >= cutbin ----
    for (int p = tid; p < P; p += 256) {
        float conf = mc[(size_t)p * C_CLASSES + c];
        if (conf > 0.3f) {
            float c0 = bc[2 * p], c1 = bc[2 * p + 1];
            if (arm_pos_f(c0, c1) >= 0.01f) {
                int bin = (int)(conf * 1024.0f);
                bin = bin > (NBINS - 1) ? (NBINS - 1) : bin;
                if (bin >= cutbin) {
                    int pos = atomicAdd(&cnt_s, 1);
                    if (pos < CAND_CAP) {
                        keys[pos] = ((uint64_t)__float_as_uint(conf) << 32) |
                                    (uint32_t)(~(uint32_t)p);
                    }
                }
            }
        }
    }
    __syncthreads();
    int n = cnt_s;
    if (n > CAND_CAP) n = CAND_CAP;

    // ---- bitonic sort descending (value desc, index asc via ~p) ----
    int np2 = 1;
    while (np2 < n) np2 <<= 1;
    if (np2 < 2) np2 = 2;
    for (int i = n + tid; i < np2; i += 256) keys[i] = 0ull;
    __syncthreads();
    for (int kk = 2; kk <= np2; kk <<= 1) {
        for (int j = kk >> 1; j > 0; j >>= 1) {
            for (int i = tid; i < np2; i += 256) {
                int ixj = i ^ j;
                if (ixj > i) {
                    uint64_t a = keys[i], bb = keys[ixj];
                    bool desc = ((i & kk) == 0);
                    if (desc ? (a < bb) : (a > bb)) {
                        keys[i] = bb;
                        keys[ixj] = a;
                    }
                }
            }
            __syncthreads();
        }
    }
    __syncthreads();

    // ---- greedy NMS on wave 0; candidates sorted => selection = first alive ----
    const int m = n < TOPK ? n : TOPK;
    if (tid >= 64) return;
    const int l = tid;
    const long long base = (long long)b * P;

    float s0f = 0.0f, s1f = 0.0f, a0 = 0.0f, a1 = 0.0f;
    float4 bx0 = {0, 0, 0, 0}, bx1 = {0, 0, 0, 0};
    bool al0 = (l < m), al1 = (l + 64 < m);
    if (al0) {
        uint64_t k = keys[l];
        s0f = __uint_as_float((uint32_t)(k >> 32));
        int p = (int)(~(uint32_t)k);
        decode_box(priors, bi_loc, ml_loc, base, p, &bx0, &a0);
    }
    if (al1) {
        uint64_t k = keys[l + 64];
        s1f = __uint_as_float((uint32_t)(k >> 32));
        int p = (int)(~(uint32_t)k);
        decode_box(priors, bi_loc, ml_loc, base, p, &bx1, &a1);
    }

    int row = 0;
    while (true) {
        unsigned long long bal0 = __ballot(al0);
        unsigned long long bal1 = __ballot(al1);
        if (!(bal0 | bal1)) break;
        int sel;
        if (bal0) sel = __ffsll(bal0) - 1;
        else sel = 64 + __ffsll(bal1) - 1;
        const bool hi = sel >= 64;
        const int sl = sel & 63;
        float ss  = __shfl(hi ? s1f  : s0f,  sl);
        float sx1 = __shfl(hi ? bx1.x : bx0.x, sl);
        float sy1 = __shfl(hi ? bx1.y : bx0.y, sl);
        float sx2 = __shfl(hi ? bx1.z : bx0.z, sl);
        float sy2 = __shfl(hi ? bx1.w : bx0.w, sl);
        float sA  = __shfl(hi ? a1   : a0,   sl);
        if (l == 0) {
            float* r = slab + row * 5;
            r[0] = ss; r[1] = sx1; r[2] = sy1; r[3] = sx2; r[4] = sy2;
        }
        row++;
        if (al0) {
            float iou = iou_f(bx0, a0, sx1, sy1, sx2, sy2, sA);
            al0 = (iou <= 0.45f) && (l != sel);
        }
        if (al1) {
            float iou = iou_f(bx1, a1, sx1, sy1, sx2, sy2, sA);
            al1 = (iou <= 0.45f) && (l + 64 != sel);
        }
    }
}

extern "C" void kernel_launch(void* const* d_in, const int* in_sizes, int n_in,
                              void* d_out, int out_size, void* d_ws, size_t ws_size,
                              hipStream_t stream) {
    const float* bi_loc  = (const float*)d_in[0];
    const float* bi_conf = (const float*)d_in[1];
    const float* ml_loc  = (const float*)d_in[2];
    const float* ml_conf = (const float*)d_in[3];
    const float* priors  = (const float*)d_in[4];
    float* out = (float*)d_out;

    const int P = in_sizes[4] / 4;
    const int B = in_sizes[0] / (4 * P);

    dim3 grid(B * (C_CLASSES - 1));
    detect_kernel<<<grid, 256, 0, stream>>>(bi_loc, bi_conf, ml_loc, ml_conf,
                                            priors, out, B, P);
}